// Round 1
// baseline (346.085 us; speedup 1.0000x reference)
//
#include <hip/hip_runtime.h>

#define S_LEN 2048
#define DM 768
#define NH 12
#define DH 64
#define BATCH 2

typedef __attribute__((ext_vector_type(8))) short bf16x8;
typedef __attribute__((ext_vector_type(4))) float f32x4;

__device__ __forceinline__ unsigned short f2bf(float f) {
  union { float f; unsigned u; } v; v.f = f;
  unsigned r = (v.u + 0x7fffu + ((v.u >> 16) & 1u)) >> 16;
  return (unsigned short)r;
}

// ---------------- Fused Q/K/V projection GEMM ----------------
// C = X @ W + b, X fp32 [4096][768], W fp32 [768][768] ([in][out]).
// Output bf16 [4096][768]. blockIdx.z selects Q(0)/K(1)/V(2); Q scaled by 1/8.
#define BM 128
#define BN 128
#define BK 32
#define LDPAD 40  // row stride (elems) for LDS tiles: 80B rows -> 16B aligned, 2-way banks max

__global__ __launch_bounds__(256) void qkv_gemm(
    const float* __restrict__ X,
    const float* __restrict__ Wq, const float* __restrict__ bq,
    const float* __restrict__ Wk, const float* __restrict__ bk,
    const float* __restrict__ Wv, const float* __restrict__ bv,
    unsigned short* __restrict__ Qo, unsigned short* __restrict__ Ko,
    unsigned short* __restrict__ Vo)
{
  const int z = blockIdx.z;
  const float* W    = (z == 0) ? Wq : (z == 1) ? Wk : Wv;
  const float* bias = (z == 0) ? bq : (z == 1) ? bk : bv;
  unsigned short* Out = (z == 0) ? Qo : (z == 1) ? Ko : Vo;
  const float scale = (z == 0) ? 0.125f : 1.0f;

  __shared__ __align__(16) unsigned short Al[BM][LDPAD];  // [m][k]
  __shared__ __align__(16) unsigned short Bl[BN][LDPAD];  // [n][k] (transposed W tile)

  const int t = threadIdx.x;
  const int wv = t >> 6, lane = t & 63;
  const int g = lane >> 4, c = lane & 15;
  const int wm = (wv >> 1) * 64, wn = (wv & 1) * 64;
  const int m0 = blockIdx.y * BM, n0 = blockIdx.x * BN;

  f32x4 acc[4][4];
  #pragma unroll
  for (int i = 0; i < 4; ++i)
    #pragma unroll
    for (int j = 0; j < 4; ++j) {
      float bb = bias[n0 + wn + j * 16 + c];
      f32x4 a4 = {bb, bb, bb, bb};
      acc[i][j] = a4;
    }

  const int a_m = t >> 1, a_k = (t & 1) * 16;
  const int b_k = t >> 3, b_n = (t & 7) * 16;

  for (int kt = 0; kt < DM / BK; ++kt) {
    const int k0 = kt * BK;
    __syncthreads();
    {  // stage A tile: X rows m0..m0+127, cols k0..k0+31 -> bf16
      const float* src = X + (size_t)(m0 + a_m) * DM + k0 + a_k;
      bf16x8 t0, t1;
      #pragma unroll
      for (int j = 0; j < 8; ++j) { t0[j] = (short)f2bf(src[j]); t1[j] = (short)f2bf(src[8 + j]); }
      *(bf16x8*)&Al[a_m][a_k] = t0;
      *(bf16x8*)&Al[a_m][a_k + 8] = t1;
    }
    {  // stage B tile transposed: W[k][n] -> Bl[n][k]
      const float* src = W + (size_t)(k0 + b_k) * DM + n0 + b_n;
      #pragma unroll
      for (int j = 0; j < 16; ++j) Bl[b_n + j][b_k] = f2bf(src[j]);
    }
    __syncthreads();
    bf16x8 af[4], bfr[4];
    #pragma unroll
    for (int i = 0; i < 4; ++i) af[i]  = *(const bf16x8*)&Al[wm + i * 16 + c][8 * g];
    #pragma unroll
    for (int j = 0; j < 4; ++j) bfr[j] = *(const bf16x8*)&Bl[wn + j * 16 + c][8 * g];
    #pragma unroll
    for (int i = 0; i < 4; ++i)
      #pragma unroll
      for (int j = 0; j < 4; ++j)
        acc[i][j] = __builtin_amdgcn_mfma_f32_16x16x32_bf16(af[i], bfr[j], acc[i][j], 0, 0, 0);
  }

  #pragma unroll
  for (int i = 0; i < 4; ++i)
    #pragma unroll
    for (int j = 0; j < 4; ++j)
      #pragma unroll
      for (int r = 0; r < 4; ++r) {
        const int m = m0 + wm + i * 16 + 4 * g + r;
        const int n = n0 + wn + j * 16 + c;
        Out[(size_t)m * DM + n] = f2bf(acc[i][j][r] * scale);
      }
}

// ---------------- Fused attention ----------------
// One block per (b, h, 64-row q-tile). 4 waves, each owns 16 q-rows.
// Pass 1: online row max+sum over all K tiles. Pass 2: recompute scores,
// write normalized P (fp32), accumulate O = P@V via MFMA.
#define QB 64
#define KB 64

__global__ __launch_bounds__(256) void attn_fused(
    const unsigned short* __restrict__ Qb,
    const unsigned short* __restrict__ Kb,
    const unsigned short* __restrict__ Vb,
    const float* __restrict__ mask,   // [B][S]
    float* __restrict__ ctx,          // [B][S][768]
    float* __restrict__ Pout)         // [B][H][S][S]
{
  const int b = blockIdx.z, h = blockIdx.y, qt = blockIdx.x;
  const int t = threadIdx.x, wv = t >> 6, lane = t & 63;
  const int g = lane >> 4, c = lane & 15;
  const int q0 = qt * QB + wv * 16;

  __shared__ __align__(16) unsigned short Vt[DH][72];      // [d][kk], 144B rows
  __shared__ __align__(16) unsigned short Pl[4][16][72];   // per-wave [q][kk]

  // Q fragments (A-layout: row=c, k=8g..8g+7), persist in registers
  const unsigned short* qp = Qb + (size_t)(b * S_LEN + q0 + c) * DM + h * DH + 8 * g;
  const bf16x8 aq0 = *(const bf16x8*)qp;
  const bf16x8 aq1 = *(const bf16x8*)(qp + 32);

  const unsigned short* kbase = Kb + (size_t)b * S_LEN * DM + h * DH + 8 * g;
  const float* mrow = mask + (size_t)b * S_LEN;

  float m[4], l[4];
  #pragma unroll
  for (int j = 0; j < 4; ++j) { m[j] = -1e30f; l[j] = 0.f; }

  // ---- pass 1: row max + sum ----
  for (int kt = 0; kt < S_LEN / KB; ++kt) {
    f32x4 s[4];
    #pragma unroll
    for (int sub = 0; sub < 4; ++sub) {
      const unsigned short* kp = kbase + (size_t)(kt * KB + sub * 16 + c) * DM;
      bf16x8 bk0 = *(const bf16x8*)kp;
      bf16x8 bk1 = *(const bf16x8*)(kp + 32);
      f32x4 zz = {0.f, 0.f, 0.f, 0.f};
      zz = __builtin_amdgcn_mfma_f32_16x16x32_bf16(aq0, bk0, zz, 0, 0, 0);
      s[sub] = __builtin_amdgcn_mfma_f32_16x16x32_bf16(aq1, bk1, s[sub] = zz, 0, 0, 0);
      const float mk = mrow[kt * KB + sub * 16 + c];
      #pragma unroll
      for (int j = 0; j < 4; ++j) s[sub][j] += mk;
    }
    #pragma unroll
    for (int j = 0; j < 4; ++j) {
      float tm = fmaxf(fmaxf(s[0][j], s[1][j]), fmaxf(s[2][j], s[3][j]));
      tm = fmaxf(tm, __shfl_xor(tm, 1));
      tm = fmaxf(tm, __shfl_xor(tm, 2));
      tm = fmaxf(tm, __shfl_xor(tm, 4));
      tm = fmaxf(tm, __shfl_xor(tm, 8));
      const float mn = fmaxf(m[j], tm);
      float es = __expf(s[0][j] - mn) + __expf(s[1][j] - mn) +
                 __expf(s[2][j] - mn) + __expf(s[3][j] - mn);
      es += __shfl_xor(es, 1);
      es += __shfl_xor(es, 2);
      es += __shfl_xor(es, 4);
      es += __shfl_xor(es, 8);
      l[j] = l[j] * __expf(m[j] - mn) + es;
      m[j] = mn;
    }
  }
  float invl[4];
  #pragma unroll
  for (int j = 0; j < 4; ++j) invl[j] = 1.f / l[j];

  f32x4 o[4];
  #pragma unroll
  for (int dt = 0; dt < 4; ++dt) { f32x4 zz = {0.f, 0.f, 0.f, 0.f}; o[dt] = zz; }

  float* prow = Pout + (size_t)(b * NH + h) * S_LEN * S_LEN;
  const int v_kk = t >> 2, v_d0 = (t & 3) * 16;

  // ---- pass 2: recompute scores, write P, accumulate PV ----
  for (int kt = 0; kt < S_LEN / KB; ++kt) {
    __syncthreads();
    {  // stage V tile transposed into LDS: Vt[d][kk]
      const unsigned short* vp = Vb + (size_t)(b * S_LEN + kt * KB + v_kk) * DM + h * DH + v_d0;
      bf16x8 v0 = *(const bf16x8*)vp;
      bf16x8 v1 = *(const bf16x8*)(vp + 8);
      #pragma unroll
      for (int j = 0; j < 8; ++j) {
        Vt[v_d0 + j][v_kk]     = (unsigned short)v0[j];
        Vt[v_d0 + 8 + j][v_kk] = (unsigned short)v1[j];
      }
    }
    __syncthreads();

    f32x4 s[4];
    #pragma unroll
    for (int sub = 0; sub < 4; ++sub) {
      const unsigned short* kp = kbase + (size_t)(kt * KB + sub * 16 + c) * DM;
      bf16x8 bk0 = *(const bf16x8*)kp;
      bf16x8 bk1 = *(const bf16x8*)(kp + 32);
      f32x4 zz = {0.f, 0.f, 0.f, 0.f};
      zz = __builtin_amdgcn_mfma_f32_16x16x32_bf16(aq0, bk0, zz, 0, 0, 0);
      s[sub] = __builtin_amdgcn_mfma_f32_16x16x32_bf16(aq1, bk1, zz, 0, 0, 0);
      const float mk = mrow[kt * KB + sub * 16 + c];
      #pragma unroll
      for (int j = 0; j < 4; ++j) s[sub][j] += mk;
    }
    #pragma unroll
    for (int sub = 0; sub < 4; ++sub) {
      #pragma unroll
      for (int j = 0; j < 4; ++j) {
        const float p = __expf(s[sub][j] - m[j]) * invl[j];
        prow[(size_t)(q0 + 4 * g + j) * S_LEN + kt * KB + sub * 16 + c] = p;
        Pl[wv][4 * g + j][sub * 16 + c] = f2bf(p);
      }
    }
    // PV: A = P (from per-wave LDS, A-layout), B = V (from Vt, contiguous kk)
    #pragma unroll
    for (int ks = 0; ks < 2; ++ks) {
      const bf16x8 pa = *(const bf16x8*)&Pl[wv][c][ks * 32 + 8 * g];
      #pragma unroll
      for (int dt = 0; dt < 4; ++dt) {
        const bf16x8 bv8 = *(const bf16x8*)&Vt[dt * 16 + c][ks * 32 + 8 * g];
        o[dt] = __builtin_amdgcn_mfma_f32_16x16x32_bf16(pa, bv8, o[dt], 0, 0, 0);
      }
    }
  }

  #pragma unroll
  for (int dt = 0; dt < 4; ++dt)
    #pragma unroll
    for (int j = 0; j < 4; ++j)
      ctx[(size_t)(b * S_LEN + q0 + 4 * g + j) * DM + h * DH + dt * 16 + c] = o[dt][j];
}

extern "C" void kernel_launch(void* const* d_in, const int* in_sizes, int n_in,
                              void* d_out, int out_size, void* d_ws, size_t ws_size,
                              hipStream_t stream) {
  const float* hs   = (const float*)d_in[0];
  const float* mask = (const float*)d_in[1];
  const float* Wq = (const float*)d_in[2];
  const float* bq = (const float*)d_in[3];
  const float* Wk = (const float*)d_in[4];
  const float* bk = (const float*)d_in[5];
  const float* Wv = (const float*)d_in[6];
  const float* bv = (const float*)d_in[7];

  const size_t MT = (size_t)BATCH * S_LEN * DM;  // 4096*768
  unsigned short* Qb = (unsigned short*)d_ws;
  unsigned short* Kb = Qb + MT;
  unsigned short* Vb = Kb + MT;

  float* ctx  = (float*)d_out;
  float* Pout = ctx + MT;  // context is B*S*768 floats, then P

  qkv_gemm<<<dim3(DM / BN, (BATCH * S_LEN) / BM, 3), 256, 0, stream>>>(
      hs, Wq, bq, Wk, bk, Wv, bv, Qb, Kb, Vb);
  attn_fused<<<dim3(S_LEN / QB, NH, BATCH), 256, 0, stream>>>(
      Qb, Kb, Vb, mask, ctx, Pout);
}